// Round 6
// baseline (307.801 us; speedup 1.0000x reference)
//
#include <hip/hip_runtime.h>
#include <math.h>

#define D 128
#define NBUCK_MAX 1024     // runtime nbuck = ceil(N/128) = 782
#define PER       6144     // edges per binning chunk (payload fits 24 KB LDS); nchunk = ceil(E/PER)
#define NCHUNK_PAD 512     // padded chunk count for fixed 9-step binary search (nchunk=261 at E=1.6M)
#define CAPB      4096     // dense col_idx slots per bucket (lambda=2048 + 128 self slots)
#define CAPE      2600     // LDS edge buffer per bucket (lambda=2048, +12 sigma)

typedef unsigned short u16;
typedef unsigned int   u32;
typedef __attribute__((ext_vector_type(8))) short short8;   // 8 bf16 = 4 VGPRs (MFMA A/B frag)
typedef __attribute__((ext_vector_type(4))) float f32x4;    // MFMA C/D frag
typedef __attribute__((ext_vector_type(2))) float f32x2;

static __device__ __forceinline__ u16 f32_to_bf16(float f) {
    u32 u = __builtin_bit_cast(u32, f);
    u32 r = (u + 0x7FFFu + ((u >> 16) & 1u)) >> 16;          // RNE
    return (u16)r;
}
static __device__ __forceinline__ u32 pack_bf16x2(float lo, float hi) {
    return (u32)f32_to_bf16(lo) | ((u32)f32_to_bf16(hi) << 16);
}
static __device__ __forceinline__ float bf16lo_to_f32(u32 v) {
    return __builtin_bit_cast(float, v << 16);
}
static __device__ __forceinline__ float bf16hi_to_f32(u32 v) {
    return __builtin_bit_cast(float, v & 0xFFFF0000u);
}

// ---------------- dispatch 1: LDS bucket-sort binning + goff scan + out zero + W/Wf pack ----------------
// Chunk c (c < nchunk) sorts its PER edges by dst-bucket in LDS, flushes COALESCED runs to
// edgeBuf[c*PER ...]. offTab is TRANSPOSED [bucket][chunk] (stride NCHUNK_PAD): prep writes are
// scattered u16s into a 1 MB L2-resident table; finalize reads become contiguous per-bucket runs.
__global__ __launch_bounds__(512) void prep_place(const int* __restrict__ src, const int* __restrict__ dst,
                                                  int E, int nbuck, int nchunk,
                                                  u32* __restrict__ edgeBuf, u16* __restrict__ offTab,
                                                  const float* __restrict__ W0, const float* __restrict__ W1,
                                                  u16* __restrict__ Wp0, u16* __restrict__ Wp1,
                                                  const float* __restrict__ Wf, float* __restrict__ Wfp,
                                                  const int* __restrict__ gsz, int G, int* __restrict__ goff,
                                                  float* __restrict__ outZ) {
    const int b = blockIdx.x;
    const int tid = threadIdx.x;
    if (b < nchunk) {
        __shared__ int cnt[NBUCK_MAX];      // counts -> exclusive-scan cursors
        __shared__ u32 pay[PER];            // 24 KB sorted payload
        for (int i = tid; i < nbuck; i += 512) cnt[i] = 0;
        __syncthreads();
        const int s = b * PER, e = min(E, s + PER);
        for (int i = s + tid; i < e; i += 512) atomicAdd(&cnt[dst[i] >> 7], 1);
        __syncthreads();
        if (tid < 64) {                     // wave 0: serial-carry exclusive scan, write offTab col b
            int carry = 0;
            int rounds = (nbuck + 63) >> 6;
            for (int r = 0; r < rounds; r++) {
                int i = r * 64 + tid;
                int v = (i < nbuck) ? cnt[i] : 0;
                int incl = v;
                #pragma unroll
                for (int off = 1; off < 64; off <<= 1) { int t = __shfl_up(incl, off); if (tid >= off) incl += t; }
                int excl = carry + incl - v;
                if (i < nbuck) { offTab[(size_t)i * NCHUNK_PAD + b] = (u16)excl; cnt[i] = excl; }
                carry += __shfl(incl, 63);
            }
            if (tid == 0) offTab[(size_t)nbuck * NCHUNK_PAD + b] = (u16)carry;   // sentinel row
        }
        __syncthreads();
        for (int i = s + tid; i < e; i += 512) {
            int d = dst[i];
            int pos = atomicAdd(&cnt[d >> 7], 1);
            pay[pos] = (u32)src[i] | ((u32)(d & 127) << 20);
        }
        __syncthreads();
        const int m = e - s;
        for (int i = tid; i < m; i += 512) edgeBuf[(size_t)b * PER + i] = pay[i];
    } else if (b == nchunk) {
        // exclusive scan of graph sizes -> goff[0..G] (sentinel); zero the fused-mean output
        __shared__ int wsum[8];
        int base = tid * 4;
        int v[4];
        #pragma unroll
        for (int k = 0; k < 4; k++) v[k] = (base + k < G) ? gsz[base + k] : 0;
        int s = v[0] + v[1] + v[2] + v[3];
        int lane = tid & 63;
        int incl = s;
        #pragma unroll
        for (int off = 1; off < 64; off <<= 1) { int t = __shfl_up(incl, off); if (lane >= off) incl += t; }
        int wv = tid >> 6;
        if (lane == 63) wsum[wv] = incl;
        __syncthreads();
        int woff = 0;
        for (int w = 0; w < wv; w++) woff += wsum[w];
        int run = woff + incl - s;
        #pragma unroll
        for (int k = 0; k < 4; k++) {
            if (base + k <= G) goff[base + k] = run;
            run += v[k];
        }
        for (int i = tid; i < G * 12; i += 512) outZ[i] = 0.f;
    } else if (b == nchunk + 1) {
        // Wf pack: Wfp[lane*24 + k*3 + j] = Wf[((lane&15)*8+k)*12 + 3*(lane>>4)+j]
        for (int i = tid; i < 64 * 24; i += 512) {
            int lane = i / 24, r = i % 24, k = r / 3, j = r % 3;
            Wfp[i] = Wf[(((lane & 15) * 8) + k) * 12 + 3 * (lane >> 4) + j];
        }
    } else {
        // W pack: Wp[((nt*4+kt)*64 + lane)*8 + j] = bf16( W[kt*32+(lane>>4)*8+j][nt*16+(lane&15)] )
        int gidx = (b - (nchunk + 2)) * 512 + tid;          // 0 .. 32767
        const float* W = (gidx < 128 * 128) ? W0 : W1;
        u16* Wp = (gidx < 128 * 128) ? Wp0 : Wp1;
        int idx = gidx & (128 * 128 - 1);
        int j = idx & 7, lane = (idx >> 3) & 63, kt = (idx >> 9) & 3, nt = idx >> 11;
        int k = kt * 32 + ((lane >> 4) << 3) + j;
        int n = nt * 16 + (lane & 15);
        Wp[idx] = f32_to_bf16(W[k * 128 + n]);
    }
}

// ---------------- MFMA GEMM core (64-row tiles; used by finalize_gemm0) ----------------
static __device__ __forceinline__ void gemm_body(const short8 af[4], const u16* __restrict__ Wp,
                                                 u16* __restrict__ outb, int N, int row0,
                                                 int tid, int wave, int lane, int quad, int l16,
                                                 u16* Cs) {
    f32x4 acc[8];
    #pragma unroll
    for (int nt = 0; nt < 8; nt++) acc[nt] = (f32x4){0.f, 0.f, 0.f, 0.f};
    #pragma unroll
    for (int kt = 0; kt < 4; kt++) {
        #pragma unroll
        for (int nt = 0; nt < 8; nt++) {
            short8 bf = *(const short8*)(Wp + ((size_t)(nt * 4 + kt) * 64 + lane) * 8);
            acc[nt] = __builtin_amdgcn_mfma_f32_16x16x32_bf16(af[kt], bf, acc[nt], 0, 0, 0);
        }
    }
    // C layout col=lane&15, row=quad*4+reg -> LDS transpose -> coalesced bf16 store
    #pragma unroll
    for (int nt = 0; nt < 8; nt++) {
        #pragma unroll
        for (int r = 0; r < 4; r++) {
            int rl = wave * 16 + quad * 4 + r;
            Cs[rl * 136 + nt * 16 + l16] = f32_to_bf16(acc[nt][r]);
        }
    }
    __syncthreads();
    for (int i = tid; i < 64 * 16; i += 256) {
        int row = i >> 4, chunk = i & 15;
        int grow = row0 + row;
        if (grow <= N)      // row N = zero pad row for agg tail lanes
            *(uint4*)(outb + (size_t)grow * 128 + chunk * 8) =
                *(const uint4*)(Cs + row * 136 + chunk * 8);
    }
}

// ---------------- dispatch 2: csr finalize (run-table compact, SELF-EDGE inserted) + layer-0 gemm ----------------
__global__ __launch_bounds__(256) void finalize_gemm0(const u32* __restrict__ edgeBuf,
                                                      const u16* __restrict__ offTab,
                                                      int2* __restrict__ rowse, int* __restrict__ col_idx,
                                                      int nbuck, int nchunk,
                                                      const float* __restrict__ A, const u16* __restrict__ Wp,
                                                      u16* __restrict__ outb, int N) {
    __shared__ u16 Cs[64 * 136];     // 17408 B, reused as int scratch by the finalize branch
    const int tid = threadIdx.x;
    if ((int)blockIdx.x < nbuck) {
        int* iCs   = (int*)Cs;
        u32* eL    = (u32*)iCs;          // [0, CAPE)  compacted edges
        int* hist  = iCs + CAPE;         // 128
        int* lcur  = iCs + CAPE + 128;   // 128
        int* scnt  = iCs + CAPE + 256;   // 512: packed (off<<16)|cnt per chunk
        int* sbase = iCs + CAPE + 768;   // 513 chunk bases (sentinel)  -> total 15524 B < 17408
        const int b = blockIdx.x;
        // coalesced: rows b and b+1 of transposed offTab are contiguous u16 runs
        for (int c = tid; c < NCHUNK_PAD; c += 256) {
            if (c < nchunk) {
                int off0 = offTab[(size_t)b * NCHUNK_PAD + c];
                int off1 = offTab[(size_t)(b + 1) * NCHUNK_PAD + c];
                scnt[c] = (off0 << 16) | (off1 - off0);
            } else scnt[c] = 0;
        }
        if (tid < 128) hist[tid] = 0;
        __syncthreads();
        if (tid < 64) {              // wave 0: exclusive scan of padded chunk counts + total sentinel
            int carry = 0;
            #pragma unroll
            for (int c4 = 0; c4 < NCHUNK_PAD / 64; c4++) {
                int v = scnt[c4 * 64 + tid] & 0xFFFF;
                int incl = v;
                #pragma unroll
                for (int off = 1; off < 64; off <<= 1) { int t = __shfl_up(incl, off); if (tid >= off) incl += t; }
                sbase[c4 * 64 + tid] = carry + incl - v;
                carry += __shfl(incl, 63);
            }
            if (tid == 0) sbase[NCHUNK_PAD] = carry;
        }
        __syncthreads();
        const int nE = min(sbase[NCHUNK_PAD], CAPE);
        // compact: output position p -> chunk via 9-step binary search; read that chunk's run
        for (int p = tid; p < nE; p += 256) {
            int lo = 0, hi = NCHUNK_PAD;
            #pragma unroll
            for (int s = 0; s < 9; s++) {
                int mid = (lo + hi) >> 1;
                if (sbase[mid] <= p) lo = mid; else hi = mid;
            }
            int rec = scnt[lo];
            eL[p] = edgeBuf[(size_t)lo * PER + (rec >> 16) + (p - sbase[lo])];
        }
        __syncthreads();
        for (int i = tid; i < nE; i += 256)
            atomicAdd(&hist[(int)(eL[i] >> 20)], 1);
        __syncthreads();
        if (tid < 64) {
            int v0 = hist[tid * 2], v1 = hist[tid * 2 + 1];
            int s = v0 + v1;
            int incl = s;
            #pragma unroll
            for (int off = 1; off < 64; off <<= 1) { int t = __shfl_up(incl, off); if (tid >= off) incl += t; }
            int excl = incl - s;
            // self-edge insertion: local node i's range grows by 1; slot 0 of each range = self.
            int le0 = excl + tid * 2;            // local start of node tid*2 (incl. preceding self slots)
            int le1 = le0 + v0 + 1;              // local start of node tid*2+1
            lcur[tid * 2]     = le0 + 1;         // neighbor scatter starts after the self slot
            lcur[tid * 2 + 1] = le1 + 1;
            int node = b * 128 + tid * 2;
            int st0 = b * CAPB + le0, st1 = b * CAPB + le1;
            if (node < N)     { rowse[node]     = make_int2(st0, st1);          col_idx[st0] = node; }
            if (node + 1 < N) { rowse[node + 1] = make_int2(st1, st1 + v1 + 1); col_idx[st1] = node + 1; }
        }
        __syncthreads();
        for (int i = tid; i < nE; i += 256) {
            u32 p = eL[i];
            int pos = atomicAdd(&lcur[p >> 20], 1);
            col_idx[b * CAPB + pos] = (int)(p & 0xFFFFFu);
        }
    } else {
        const int bid = blockIdx.x - nbuck;
        const int wave = tid >> 6, lane = tid & 63, quad = lane >> 4, l16 = lane & 15;
        const int row0 = bid * 64;
        const int arow = row0 + wave * 16 + l16;
        union { u32 u[4]; short8 s; } cv;
        short8 af[4];
        if (arow < N) {
            const float* ab = A + (size_t)arow * 128 + quad * 8;
            #pragma unroll
            for (int kt = 0; kt < 4; kt++) {
                float4 x0 = *(const float4*)(ab + kt * 32);
                float4 x1 = *(const float4*)(ab + kt * 32 + 4);
                cv.u[0] = pack_bf16x2(x0.x, x0.y);
                cv.u[1] = pack_bf16x2(x0.z, x0.w);
                cv.u[2] = pack_bf16x2(x1.x, x1.y);
                cv.u[3] = pack_bf16x2(x1.z, x1.w);
                af[kt] = cv.s;
            }
        } else {
            short8 z = {0, 0, 0, 0, 0, 0, 0, 0};
            #pragma unroll
            for (int kt = 0; kt < 4; kt++) af[kt] = z;
        }
        gemm_body(af, Wp, outb, N, row0, tid, wave, lane, quad, l16, Cs);
    }
}

// ---------------- shared gather core (two nodes per wave, self-edge comes from CSR) ----------------
static __device__ __forceinline__ void add_row(f32x2* acc, uint4 u) {
    acc[0] += (f32x2){bf16lo_to_f32(u.x), bf16hi_to_f32(u.x)};
    acc[1] += (f32x2){bf16lo_to_f32(u.y), bf16hi_to_f32(u.y)};
    acc[2] += (f32x2){bf16lo_to_f32(u.z), bf16hi_to_f32(u.z)};
    acc[3] += (f32x2){bf16lo_to_f32(u.w), bf16hi_to_f32(u.w)};
}

// gathers TWO nodes per wave -> relu(sum + bias) in r0/r1.  (at the random-fetch roofline:
// FETCH ~= 7 XCD x 25.6MB compulsory fills @ ~2.7 TB/s; structural variants all land at ~72us)
// All tail paths are INLINE (a noinline helper demoted accs to scratch; round-1 post-mortem).
static __device__ __forceinline__ void gather2(const u16* __restrict__ xwb, const int2* __restrict__ rowse,
                                               const int* __restrict__ col_idx, const float* __restrict__ bias,
                                               int wid0, int wid1, int lane, int N, int q, int d8,
                                               float r0[8], float r1[8]) {
    f32x2 accA[4], accB[4];
    #pragma unroll
    for (int t = 0; t < 4; t++) { accA[t] = (f32x2){0.f, 0.f}; accB[t] = (f32x2){0.f, 0.f}; }
    int2 seA = rowse[wid0];
    int2 seB = rowse[wid1];
    int ia = seA.x + lane, ib = seB.x + lane;
    int jA = (ia < seA.y) ? col_idx[ia] : N;     // tail / overhang lanes -> shared zero row
    int jB = (ib < seB.y) ? col_idx[ib] : N;
    // cnt values are wave-uniform (wid0/wid1 uniform per wave) -> scalarize for scalar branches
    int cntA = __builtin_amdgcn_readfirstlane(min(64, seA.y - seA.x));
    int cntB = __builtin_amdgcn_readfirstlane(min(64, seB.y - seB.x));
    int mx = max(cntA, cntB);
    for (int i = 0; i < mx; i += 8) {
        uint4 ra0, ra1, rb0, rb1;
        const bool dA = i < cntA, dB = i < cntB;   // wave-uniform
        if (dA) {
            int a0 = __shfl(jA, i + q);
            int a1 = __shfl(jA, i + 4 + q);
            ra0 = *(const uint4*)(xwb + (size_t)a0 * D + d8);
            ra1 = *(const uint4*)(xwb + (size_t)a1 * D + d8);
        }
        if (dB) {
            int b0 = __shfl(jB, i + q);
            int b1 = __shfl(jB, i + 4 + q);
            rb0 = *(const uint4*)(xwb + (size_t)b0 * D + d8);
            rb1 = *(const uint4*)(xwb + (size_t)b1 * D + d8);
        }
        if (dA) { add_row(accA, ra0); add_row(accA, ra1); }
        if (dB) { add_row(accB, rb0); add_row(accB, rb1); }
    }
    // cold long-degree remainder (deg+1 > 64), fully inlined
    for (int e = seA.x + 64; e < seA.y; e += 64) {
        int idx = e + lane;
        int j = (idx < seA.y) ? col_idx[idx] : N;
        int cnt = min(64, seA.y - e);
        for (int i = 0; i < cnt; i += 8) {
            int j0 = __shfl(j, i + q);
            int j1 = __shfl(j, i + 4 + q);
            add_row(accA, *(const uint4*)(xwb + (size_t)j0 * D + d8));
            add_row(accA, *(const uint4*)(xwb + (size_t)j1 * D + d8));
        }
    }
    for (int e = seB.x + 64; e < seB.y; e += 64) {
        int idx = e + lane;
        int j = (idx < seB.y) ? col_idx[idx] : N;
        int cnt = min(64, seB.y - e);
        for (int i = 0; i < cnt; i += 8) {
            int j0 = __shfl(j, i + q);
            int j1 = __shfl(j, i + 4 + q);
            add_row(accB, *(const uint4*)(xwb + (size_t)j0 * D + d8));
            add_row(accB, *(const uint4*)(xwb + (size_t)j1 * D + d8));
        }
    }

    float av0[8] = {accA[0].x, accA[0].y, accA[1].x, accA[1].y, accA[2].x, accA[2].y, accA[3].x, accA[3].y};
    float av1[8] = {accB[0].x, accB[0].y, accB[1].x, accB[1].y, accB[2].x, accB[2].y, accB[3].x, accB[3].y};
    #pragma unroll
    for (int t = 0; t < 8; t++) {
        av0[t] += __shfl_xor(av0[t], 16);
        av0[t] += __shfl_xor(av0[t], 32);
        av1[t] += __shfl_xor(av1[t], 16);
        av1[t] += __shfl_xor(av1[t], 32);
    }
    float4 ba = *(const float4*)(bias + d8);
    float4 bb = *(const float4*)(bias + d8 + 4);
    r0[0] = fmaxf(av0[0] + ba.x, 0.f);
    r0[1] = fmaxf(av0[1] + ba.y, 0.f);
    r0[2] = fmaxf(av0[2] + ba.z, 0.f);
    r0[3] = fmaxf(av0[3] + ba.w, 0.f);
    r0[4] = fmaxf(av0[4] + bb.x, 0.f);
    r0[5] = fmaxf(av0[5] + bb.y, 0.f);
    r0[6] = fmaxf(av0[6] + bb.z, 0.f);
    r0[7] = fmaxf(av0[7] + bb.w, 0.f);
    r1[0] = fmaxf(av1[0] + ba.x, 0.f);
    r1[1] = fmaxf(av1[1] + ba.y, 0.f);
    r1[2] = fmaxf(av1[2] + ba.z, 0.f);
    r1[3] = fmaxf(av1[3] + ba.w, 0.f);
    r1[4] = fmaxf(av1[4] + bb.x, 0.f);
    r1[5] = fmaxf(av1[5] + bb.y, 0.f);
    r1[6] = fmaxf(av1[6] + bb.z, 0.f);
    r1[7] = fmaxf(av1[7] + bb.w, 0.f);
}

// ---------------- dispatch 3: fused layer-1 aggregate + layer-1 GEMM ----------------
// block = 16 nodes, 4 waves. Wave w gathers nodes w*4..w*4+3 (two interleaved pairs) -> bf16 h rows
// in LDS (pad 136); then wave w computes output cols 32w..32w+31 via 8 MFMAs; LDS transpose; store.
__global__ __launch_bounds__(256) void agg_gemm1(const u16* __restrict__ xwb, const int2* __restrict__ rowse,
                                                 const int* __restrict__ col_idx, const float* __restrict__ bias,
                                                 const u16* __restrict__ Wp, u16* __restrict__ outb, int N) {
    __shared__ u16 hs[16 * 136];
    __shared__ u16 Cs[16 * 136];
    const int tid = threadIdx.x;
    const int wave = tid >> 6, lane = tid & 63, quad = lane >> 4, l16 = lane & 15;
    const int tile = blockIdx.x * 16;
    const int d8 = l16 * 8;
    #pragma unroll
    for (int m = 0; m < 4; m += 2) {
        int nl0 = wave * 4 + m, nl1 = nl0 + 1;
        int wid0 = tile + nl0, wid1 = tile + nl1;
        float r0[8], r1[8];
        int g0 = min(wid0, N - 1), g1 = min(wid1, N - 1);   // clamp pad nodes to a valid CSR row
        gather2(xwb, rowse, col_idx, bias, g0, g1, lane, N, quad, d8, r0, r1);
        if (quad == 0) {
            uint4 o0, o1;
            if (wid0 < N) {
                o0.x = pack_bf16x2(r0[0], r0[1]);
                o0.y = pack_bf16x2(r0[2], r0[3]);
                o0.z = pack_bf16x2(r0[4], r0[5]);
                o0.w = pack_bf16x2(r0[6], r0[7]);
            } else o0 = make_uint4(0, 0, 0, 0);
            if (wid1 < N) {
                o1.x = pack_bf16x2(r1[0], r1[1]);
                o1.y = pack_bf16x2(r1[2], r1[3]);
                o1.z = pack_bf16x2(r1[4], r1[5]);
                o1.w = pack_bf16x2(r1[6], r1[7]);
            } else o1 = make_uint4(0, 0, 0, 0);
            *(uint4*)(hs + nl0 * 136 + d8) = o0;
            *(uint4*)(hs + nl1 * 136 + d8) = o1;
        }
    }
    __syncthreads();
    // A-frags from LDS: row m = l16, k = kt*32 + quad*8 + j  (stride 136 -> <=2-way bank alias)
    short8 af[4];
    #pragma unroll
    for (int kt = 0; kt < 4; kt++)
        af[kt] = *(const short8*)(hs + l16 * 136 + kt * 32 + quad * 8);
    f32x4 acc[2];
    acc[0] = (f32x4){0.f, 0.f, 0.f, 0.f};
    acc[1] = (f32x4){0.f, 0.f, 0.f, 0.f};
    #pragma unroll
    for (int kt = 0; kt < 4; kt++) {
        #pragma unroll
        for (int t = 0; t < 2; t++) {
            int nt = wave * 2 + t;
            short8 bf = *(const short8*)(Wp + ((size_t)(nt * 4 + kt) * 64 + lane) * 8);
            acc[t] = __builtin_amdgcn_mfma_f32_16x16x32_bf16(af[kt], bf, acc[t], 0, 0, 0);
        }
    }
    // C layout col=lane&15 (within nt tile), row=quad*4+reg -> Cs transpose
    #pragma unroll
    for (int t = 0; t < 2; t++) {
        int nt = wave * 2 + t;
        #pragma unroll
        for (int r = 0; r < 4; r++)
            Cs[(quad * 4 + r) * 136 + nt * 16 + l16] = f32_to_bf16(acc[t][r]);
    }
    __syncthreads();
    // coalesced store: 16 rows x 16 uint4 chunks = 256 threads, one each
    {
        int row = tid >> 4, chunk = tid & 15;
        int grow = tile + row;
        if (grow <= N)      // row N = zero pad row for agg_head tails
            *(uint4*)(outb + (size_t)grow * 128 + chunk * 8) =
                *(const uint4*)(Cs + row * 136 + chunk * 8);
    }
}

// ---------------- dispatch 4: layer-2 aggregate + head + fused per-graph mean ----------------
// Block = 8 nodes (4 waves x 2). Per-node sigmoid outputs staged in LDS (unique slots, no atomics),
// then 12 threads flush run-length-compacted partials: ~13 global atomicAdds per block (~160 per
// graph line spread over the kernel) — NOT round-4's 1.2M critical-path atomics (that was 72->155us).
__global__ __launch_bounds__(256) void agg_head(const u16* __restrict__ xwb, const int2* __restrict__ rowse,
                                                const int* __restrict__ col_idx, const float* __restrict__ bias,
                                                const float* __restrict__ Wfp, const float* __restrict__ bfv,
                                                const int* __restrict__ goff, int G,
                                                float* __restrict__ outG, int N) {
    __shared__ float ps[8 * 12];    // per-node task outputs
    __shared__ int   gidL[8];
    __shared__ float invL[8];
    const int tid = threadIdx.x;
    const int nbase = blockIdx.x * 8;
    if (tid < 8) {
        int node = nbase + tid;
        if (node < N) {
            int lo = 0, hi = G;
            while (hi - lo > 1) { int mid = (lo + hi) >> 1; if (goff[mid] <= node) lo = mid; else hi = mid; }
            gidL[tid] = lo;
            invL[tid] = 1.f / (float)(goff[lo + 1] - goff[lo]);
        } else gidL[tid] = -1;
    }
    const int nlb = (tid >> 6) * 2;          // this wave's local node base
    const int wid0 = nbase + nlb;
    const int lane = tid & 63;
    const int q = lane >> 4;
    const int d8 = (lane & 15) * 8;
    const bool act = wid0 < N;               // wave-uniform
    float p00 = 0.f, p01 = 0.f, p02 = 0.f;
    float p10 = 0.f, p11 = 0.f, p12 = 0.f;
    if (act) {
        int wid1 = min(wid0 + 1, N - 1);
        // issue head-weight loads early (independent of gather) — 6 coalesced float4
        float w[24];
        const float* wp = Wfp + lane * 24;
        #pragma unroll
        for (int i = 0; i < 6; i++) *(float4*)(w + i * 4) = *(const float4*)(wp + i * 4);
        float r0[8], r1[8];
        gather2(xwb, rowse, col_idx, bias, wid0, wid1, lane, N, q, d8, r0, r1);
        #pragma unroll
        for (int k = 0; k < 8; k++) {
            p00 += r0[k] * w[k * 3];
            p01 += r0[k] * w[k * 3 + 1];
            p02 += r0[k] * w[k * 3 + 2];
            p10 += r1[k] * w[k * 3];
            p11 += r1[k] * w[k * 3 + 1];
            p12 += r1[k] * w[k * 3 + 2];
        }
        #pragma unroll
        for (int m = 1; m <= 8; m <<= 1) {
            p00 += __shfl_xor(p00, m);
            p01 += __shfl_xor(p01, m);
            p02 += __shfl_xor(p02, m);
            p10 += __shfl_xor(p10, m);
            p11 += __shfl_xor(p11, m);
            p12 += __shfl_xor(p12, m);
        }
    }
    if ((lane & 15) == 0) {                  // 4 lanes per wave stage 3 tasks x 2 nodes
        const int t0 = 3 * q;
        float b0 = bfv[t0], b1 = bfv[t0 + 1], b2 = bfv[t0 + 2];
        ps[nlb * 12 + t0]     = 1.f / (1.f + __expf(-(p00 + b0)));
        ps[nlb * 12 + t0 + 1] = 1.f / (1.f + __expf(-(p01 + b1)));
        ps[nlb * 12 + t0 + 2] = 1.f / (1.f + __expf(-(p02 + b2)));
        ps[(nlb + 1) * 12 + t0]     = 1.f / (1.f + __expf(-(p10 + b0)));
        ps[(nlb + 1) * 12 + t0 + 1] = 1.f / (1.f + __expf(-(p11 + b1)));
        ps[(nlb + 1) * 12 + t0 + 2] = 1.f / (1.f + __expf(-(p12 + b2)));
    }
    __syncthreads();
    if (tid < 12) {                          // run-length flush per task: ~1-2 atomics each
        const int t = tid;
        float run = 0.f;
        int cg = -1;
        #pragma unroll
        for (int n = 0; n < 8; n++) {
            int g = gidL[n];
            if (g < 0) continue;             // pad node (or duplicated clamp slot past N)
            float v = ps[n * 12 + t] * invL[n];
            if (g != cg) {
                if (cg >= 0) atomicAdd(&outG[cg * 12 + t], run);
                cg = g; run = v;
            } else run += v;
        }
        if (cg >= 0) atomicAdd(&outG[cg * 12 + t], run);
    }
}

// ---------------- launch ----------------

extern "C" void kernel_launch(void* const* d_in, const int* in_sizes, int n_in,
                              void* d_out, int out_size, void* d_ws, size_t ws_size,
                              hipStream_t stream) {
    const float* X   = (const float*)d_in[0];
    const int* edges = (const int*)d_in[1];
    const int* gsz   = (const int*)d_in[2];
    const float* W0  = (const float*)d_in[3];
    const float* b0  = (const float*)d_in[4];
    const float* W1  = (const float*)d_in[5];
    const float* b1  = (const float*)d_in[6];
    const float* Wf  = (const float*)d_in[7];
    const float* bfv = (const float*)d_in[8];
    float* out = (float*)d_out;

    const int N = in_sizes[0] / D;       // 100000
    const int E = in_sizes[1] / 2;       // 1600000
    const int G = in_sizes[2];           // 1000
    const int* esrc = edges;
    const int* edst = edges + E;
    const int nbuck = (N + 127) >> 7;    // 782
    const int nchunk = (E + PER - 1) / PER;   // 261

    // workspace layout (xwb/hb get N+64 rows: row N is the zero pad row)
    char* ws = (char*)d_ws;
    char* p = ws;
    u16* xwb     = (u16*)p;  p += (((size_t)(N + 64) * D * 2) + 255) & ~255ull;
    u16* hb      = (u16*)p;  p += (((size_t)(N + 64) * D * 2) + 255) & ~255ull;
    u16* Wp0     = (u16*)p;  p += ((size_t)128 * 128 * 2 + 255) & ~255ull;
    u16* Wp1     = (u16*)p;  p += ((size_t)128 * 128 * 2 + 255) & ~255ull;
    float* Wfp   = (float*)p; p += ((size_t)64 * 24 * 4 + 255) & ~255ull;
    u32* edgeBuf = (u32*)p;  p += (((size_t)nchunk * PER * 4) + 255) & ~255ull;              // 6.4 MB
    u16* offTab  = (u16*)p;  p += (((size_t)(NBUCK_MAX + 1) * NCHUNK_PAD * 2) + 255) & ~255ull;  // 1.05 MB
    int* col_idx = (int*)p;  p += (((size_t)nbuck * CAPB * 4) + 255) & ~255ull;              // 12.8 MB
    int2* rowse  = (int2*)p; p += (((size_t)N * 8) + 255) & ~255ull;
    int* goff    = (int*)p;

    // 1: LDS bucket-sort binning (coalesced edgeBuf runs, transposed offTab) + goff scan + out zero + packs
    prep_place<<<nchunk + 2 + 64, 512, 0, stream>>>(esrc, edst, E, nbuck, nchunk, edgeBuf, offTab,
                                                    W0, W1, Wp0, Wp1, Wf, Wfp, gsz, G, goff, out);
    // 2: CSR finalize (run-table compact, self-edge inserted) + layer-0 GEMM
    const int gemmGrid = (N + 63) / 64;
    finalize_gemm0<<<nbuck + gemmGrid, 256, 0, stream>>>(edgeBuf, offTab, rowse, col_idx, nbuck, nchunk,
                                                         X, Wp0, xwb, N);
    // 3: fused layer-1 aggregate + layer-1 GEMM (writes xw2 into hb, incl. zero row N)
    agg_gemm1<<<N / 16 + 1, 256, 0, stream>>>(xwb, rowse, col_idx, b0, Wp1, hb, N);
    // 4: layer-2 aggregate + head + fused per-graph mean (LDS-staged, ~13 atomics/block)
    const int waves2 = (N + 1) / 2;
    agg_head<<<(waves2 + 3) / 4, 256, 0, stream>>>(hb, rowse, col_idx, b1, Wfp, bfv, goff, G, out, N);
}

// Round 7
// 275.562 us; speedup vs baseline: 1.1170x; 1.1170x over previous
//
#include <hip/hip_runtime.h>
#include <math.h>

#define D 128
#define NBUCK_MAX 1024     // runtime nbuck = ceil(N/128) = 782
#define PER       6144     // edges per binning chunk (payload fits 24 KB LDS); nchunk = ceil(E/PER)
#define NCHUNK_PAD 512     // padded chunk count for fixed 9-step binary search (nchunk=261 at E=1.6M)
#define CAPB      4096     // dense col_idx slots per bucket (lambda=2048 + 128 self slots)
#define CAPE      2600     // LDS edge buffer per bucket (lambda=2048, +12 sigma)

typedef unsigned short u16;
typedef unsigned int   u32;
typedef __attribute__((ext_vector_type(8))) short short8;   // 8 bf16 = 4 VGPRs (MFMA A/B frag)
typedef __attribute__((ext_vector_type(4))) float f32x4;    // MFMA C/D frag
typedef __attribute__((ext_vector_type(2))) float f32x2;

static __device__ __forceinline__ u16 f32_to_bf16(float f) {
    u32 u = __builtin_bit_cast(u32, f);
    u32 r = (u + 0x7FFFu + ((u >> 16) & 1u)) >> 16;          // RNE
    return (u16)r;
}
static __device__ __forceinline__ u32 pack_bf16x2(float lo, float hi) {
    return (u32)f32_to_bf16(lo) | ((u32)f32_to_bf16(hi) << 16);
}
static __device__ __forceinline__ float bf16lo_to_f32(u32 v) {
    return __builtin_bit_cast(float, v << 16);
}
static __device__ __forceinline__ float bf16hi_to_f32(u32 v) {
    return __builtin_bit_cast(float, v & 0xFFFF0000u);
}

// ---------------- dispatch 1: LDS bucket-sort binning + goff scan + W/Wf pack ----------------
// Chunk c (c < nchunk) sorts its PER edges by dst-bucket in LDS, flushes COALESCED runs to
// edgeBuf[c*PER ...]. offTab is TRANSPOSED [bucket][chunk] (stride NCHUNK_PAD): prep writes are
// scattered u16s into a 1 MB L2-resident table; finalize reads become contiguous per-bucket runs.
__global__ __launch_bounds__(512) void prep_place(const int* __restrict__ src, const int* __restrict__ dst,
                                                  int E, int nbuck, int nchunk,
                                                  u32* __restrict__ edgeBuf, u16* __restrict__ offTab,
                                                  const float* __restrict__ W0, const float* __restrict__ W1,
                                                  u16* __restrict__ Wp0, u16* __restrict__ Wp1,
                                                  const float* __restrict__ Wf, float* __restrict__ Wfp,
                                                  const int* __restrict__ gsz, int G, int* __restrict__ goff) {
    const int b = blockIdx.x;
    const int tid = threadIdx.x;
    if (b < nchunk) {
        __shared__ int cnt[NBUCK_MAX];      // counts -> exclusive-scan cursors
        __shared__ u32 pay[PER];            // 24 KB sorted payload
        for (int i = tid; i < nbuck; i += 512) cnt[i] = 0;
        __syncthreads();
        const int s = b * PER, e = min(E, s + PER);
        for (int i = s + tid; i < e; i += 512) atomicAdd(&cnt[dst[i] >> 7], 1);
        __syncthreads();
        if (tid < 64) {                     // wave 0: serial-carry exclusive scan, write offTab col b
            int carry = 0;
            int rounds = (nbuck + 63) >> 6;
            for (int r = 0; r < rounds; r++) {
                int i = r * 64 + tid;
                int v = (i < nbuck) ? cnt[i] : 0;
                int incl = v;
                #pragma unroll
                for (int off = 1; off < 64; off <<= 1) { int t = __shfl_up(incl, off); if (tid >= off) incl += t; }
                int excl = carry + incl - v;
                if (i < nbuck) { offTab[(size_t)i * NCHUNK_PAD + b] = (u16)excl; cnt[i] = excl; }
                carry += __shfl(incl, 63);
            }
            if (tid == 0) offTab[(size_t)nbuck * NCHUNK_PAD + b] = (u16)carry;   // sentinel row
        }
        __syncthreads();
        for (int i = s + tid; i < e; i += 512) {
            int d = dst[i];
            int pos = atomicAdd(&cnt[d >> 7], 1);
            pay[pos] = (u32)src[i] | ((u32)(d & 127) << 20);
        }
        __syncthreads();
        const int m = e - s;
        for (int i = tid; i < m; i += 512) edgeBuf[(size_t)b * PER + i] = pay[i];
    } else if (b == nchunk) {
        // exclusive scan of graph sizes -> goff[0..G] (sentinel)
        __shared__ int wsum[8];
        int base = tid * 4;
        int v[4];
        #pragma unroll
        for (int k = 0; k < 4; k++) v[k] = (base + k < G) ? gsz[base + k] : 0;
        int s = v[0] + v[1] + v[2] + v[3];
        int lane = tid & 63;
        int incl = s;
        #pragma unroll
        for (int off = 1; off < 64; off <<= 1) { int t = __shfl_up(incl, off); if (lane >= off) incl += t; }
        int wv = tid >> 6;
        if (lane == 63) wsum[wv] = incl;
        __syncthreads();
        int woff = 0;
        for (int w = 0; w < wv; w++) woff += wsum[w];
        int run = woff + incl - s;
        #pragma unroll
        for (int k = 0; k < 4; k++) {
            if (base + k <= G) goff[base + k] = run;
            run += v[k];
        }
    } else if (b == nchunk + 1) {
        // Wf pack: Wfp[lane*24 + k*3 + j] = Wf[((lane&15)*8+k)*12 + 3*(lane>>4)+j]
        for (int i = tid; i < 64 * 24; i += 512) {
            int lane = i / 24, r = i % 24, k = r / 3, j = r % 3;
            Wfp[i] = Wf[(((lane & 15) * 8) + k) * 12 + 3 * (lane >> 4) + j];
        }
    } else {
        // W pack: Wp[((nt*4+kt)*64 + lane)*8 + j] = bf16( W[kt*32+(lane>>4)*8+j][nt*16+(lane&15)] )
        int gidx = (b - (nchunk + 2)) * 512 + tid;          // 0 .. 32767
        const float* W = (gidx < 128 * 128) ? W0 : W1;
        u16* Wp = (gidx < 128 * 128) ? Wp0 : Wp1;
        int idx = gidx & (128 * 128 - 1);
        int j = idx & 7, lane = (idx >> 3) & 63, kt = (idx >> 9) & 3, nt = idx >> 11;
        int k = kt * 32 + ((lane >> 4) << 3) + j;
        int n = nt * 16 + (lane & 15);
        Wp[idx] = f32_to_bf16(W[k * 128 + n]);
    }
}

// ---------------- MFMA GEMM core (64-row tiles; used by finalize_gemm0) ----------------
static __device__ __forceinline__ void gemm_body(const short8 af[4], const u16* __restrict__ Wp,
                                                 u16* __restrict__ outb, int N, int row0,
                                                 int tid, int wave, int lane, int quad, int l16,
                                                 u16* Cs) {
    f32x4 acc[8];
    #pragma unroll
    for (int nt = 0; nt < 8; nt++) acc[nt] = (f32x4){0.f, 0.f, 0.f, 0.f};
    #pragma unroll
    for (int kt = 0; kt < 4; kt++) {
        #pragma unroll
        for (int nt = 0; nt < 8; nt++) {
            short8 bf = *(const short8*)(Wp + ((size_t)(nt * 4 + kt) * 64 + lane) * 8);
            acc[nt] = __builtin_amdgcn_mfma_f32_16x16x32_bf16(af[kt], bf, acc[nt], 0, 0, 0);
        }
    }
    // C layout col=lane&15, row=quad*4+reg -> LDS transpose -> coalesced bf16 store
    #pragma unroll
    for (int nt = 0; nt < 8; nt++) {
        #pragma unroll
        for (int r = 0; r < 4; r++) {
            int rl = wave * 16 + quad * 4 + r;
            Cs[rl * 136 + nt * 16 + l16] = f32_to_bf16(acc[nt][r]);
        }
    }
    __syncthreads();
    for (int i = tid; i < 64 * 16; i += 256) {
        int row = i >> 4, chunk = i & 15;
        int grow = row0 + row;
        if (grow <= N)      // row N = zero pad row for agg tail lanes
            *(uint4*)(outb + (size_t)grow * 128 + chunk * 8) =
                *(const uint4*)(Cs + row * 136 + chunk * 8);
    }
}

// ---------------- dispatch 2: csr finalize (LDS sort -> COALESCED col_idx flush) + layer-0 gemm ----------------
// Round-6 lesson: the old per-edge global scatter (4B random in a 16KB window) cost ~25MB of
// write-allocate RMW; now the full per-node sort finishes in LDS and col_idx is written as one
// contiguous coalesced stream per block.
__global__ __launch_bounds__(256) void finalize_gemm0(const u32* __restrict__ edgeBuf,
                                                      const u16* __restrict__ offTab,
                                                      int2* __restrict__ rowse, int* __restrict__ col_idx,
                                                      int nbuck, int nchunk,
                                                      const float* __restrict__ A, const u16* __restrict__ Wp,
                                                      u16* __restrict__ outb, int N) {
    __shared__ int sbuf[6656];       // 26.6 KB union: finalize scratch / GEMM Cs (17.4 KB)
    const int tid = threadIdx.x;
    if ((int)blockIdx.x < nbuck) {
        u32* eL     = (u32*)sbuf;                 // [0, CAPE)        compacted edges
        int* sorted = sbuf + CAPE;                // [0, CAPE+128)    node-sorted cols (incl. self)
        int* hist   = sbuf + 2 * CAPE + 128;      // 128
        int* lcur   = sbuf + 2 * CAPE + 256;      // 128
        int* scnt   = sbuf + 2 * CAPE + 384;      // 512: packed (off<<16)|cnt per chunk
        int* sbase  = sbuf + 2 * CAPE + 896;      // 513 chunk bases (sentinel) -> 6609 ints total
        const int b = blockIdx.x;
        // coalesced: rows b and b+1 of transposed offTab are contiguous u16 runs
        for (int c = tid; c < NCHUNK_PAD; c += 256) {
            if (c < nchunk) {
                int off0 = offTab[(size_t)b * NCHUNK_PAD + c];
                int off1 = offTab[(size_t)(b + 1) * NCHUNK_PAD + c];
                scnt[c] = (off0 << 16) | (off1 - off0);
            } else scnt[c] = 0;
        }
        if (tid < 128) hist[tid] = 0;
        __syncthreads();
        if (tid < 64) {              // wave 0: exclusive scan of padded chunk counts + total sentinel
            int carry = 0;
            #pragma unroll
            for (int c4 = 0; c4 < NCHUNK_PAD / 64; c4++) {
                int v = scnt[c4 * 64 + tid] & 0xFFFF;
                int incl = v;
                #pragma unroll
                for (int off = 1; off < 64; off <<= 1) { int t = __shfl_up(incl, off); if (tid >= off) incl += t; }
                sbase[c4 * 64 + tid] = carry + incl - v;
                carry += __shfl(incl, 63);
            }
            if (tid == 0) sbase[NCHUNK_PAD] = carry;
        }
        __syncthreads();
        const int nE = min(sbase[NCHUNK_PAD], CAPE);
        // compact: output position p -> chunk via 9-step binary search; read that chunk's run
        for (int p = tid; p < nE; p += 256) {
            int lo = 0, hi = NCHUNK_PAD;
            #pragma unroll
            for (int s = 0; s < 9; s++) {
                int mid = (lo + hi) >> 1;
                if (sbase[mid] <= p) lo = mid; else hi = mid;
            }
            int rec = scnt[lo];
            eL[p] = edgeBuf[(size_t)lo * PER + (rec >> 16) + (p - sbase[lo])];
        }
        __syncthreads();
        for (int i = tid; i < nE; i += 256)
            atomicAdd(&hist[(int)(eL[i] >> 20)], 1);
        __syncthreads();
        if (tid < 64) {
            int v0 = hist[tid * 2], v1 = hist[tid * 2 + 1];
            int s = v0 + v1;
            int incl = s;
            #pragma unroll
            for (int off = 1; off < 64; off <<= 1) { int t = __shfl_up(incl, off); if (tid >= off) incl += t; }
            int excl = incl - s;
            // self-edge insertion: local node i's range grows by 1; slot 0 of each range = self.
            int le0 = excl + tid * 2;            // local start of node tid*2 (incl. preceding self slots)
            int le1 = le0 + v0 + 1;              // local start of node tid*2+1
            lcur[tid * 2]     = le0 + 1;         // neighbor scatter starts after the self slot
            lcur[tid * 2 + 1] = le1 + 1;
            int node = b * 128 + tid * 2;
            int st0 = b * CAPB + le0, st1 = b * CAPB + le1;
            if (node < N)     { rowse[node]     = make_int2(st0, st1);          sorted[le0] = node; }
            if (node + 1 < N) { rowse[node + 1] = make_int2(st1, st1 + v1 + 1); sorted[le1] = node + 1; }
        }
        __syncthreads();
        for (int i = tid; i < nE; i += 256) {
            u32 p = eL[i];
            int pos = atomicAdd(&lcur[p >> 20], 1);
            sorted[pos] = (int)(p & 0xFFFFFu);          // LDS scatter, not global
        }
        __syncthreads();
        // contiguous coalesced flush (valid prefix = nE edges + one self slot per valid node)
        const int nTot = nE + min(128, N - b * 128);
        for (int i = tid; i < nTot; i += 256)
            col_idx[b * CAPB + i] = sorted[i];
    } else {
        u16* Cs = (u16*)sbuf;
        const int bid = blockIdx.x - nbuck;
        const int wave = tid >> 6, lane = tid & 63, quad = lane >> 4, l16 = lane & 15;
        const int row0 = bid * 64;
        const int arow = row0 + wave * 16 + l16;
        union { u32 u[4]; short8 s; } cv;
        short8 af[4];
        if (arow < N) {
            const float* ab = A + (size_t)arow * 128 + quad * 8;
            #pragma unroll
            for (int kt = 0; kt < 4; kt++) {
                float4 x0 = *(const float4*)(ab + kt * 32);
                float4 x1 = *(const float4*)(ab + kt * 32 + 4);
                cv.u[0] = pack_bf16x2(x0.x, x0.y);
                cv.u[1] = pack_bf16x2(x0.z, x0.w);
                cv.u[2] = pack_bf16x2(x1.x, x1.y);
                cv.u[3] = pack_bf16x2(x1.z, x1.w);
                af[kt] = cv.s;
            }
        } else {
            short8 z = {0, 0, 0, 0, 0, 0, 0, 0};
            #pragma unroll
            for (int kt = 0; kt < 4; kt++) af[kt] = z;
        }
        gemm_body(af, Wp, outb, N, row0, tid, wave, lane, quad, l16, Cs);
    }
}

// ---------------- shared gather core (two nodes per wave, self-edge comes from CSR) ----------------
static __device__ __forceinline__ void add_row(f32x2* acc, uint4 u) {
    acc[0] += (f32x2){bf16lo_to_f32(u.x), bf16hi_to_f32(u.x)};
    acc[1] += (f32x2){bf16lo_to_f32(u.y), bf16hi_to_f32(u.y)};
    acc[2] += (f32x2){bf16lo_to_f32(u.z), bf16hi_to_f32(u.z)};
    acc[3] += (f32x2){bf16lo_to_f32(u.w), bf16hi_to_f32(u.w)};
}

// gathers TWO nodes per wave -> relu(sum + bias) in r0/r1.  (at the random-fetch roofline:
// FETCH ~= 7 XCD x 25.6MB compulsory fills @ ~2.7 TB/s; structural variants all land at ~72us)
// All tail paths are INLINE (a noinline helper demoted accs to scratch; round-1 post-mortem).
static __device__ __forceinline__ void gather2(const u16* __restrict__ xwb, const int2* __restrict__ rowse,
                                               const int* __restrict__ col_idx, const float* __restrict__ bias,
                                               int wid0, int wid1, int lane, int N, int q, int d8,
                                               float r0[8], float r1[8]) {
    f32x2 accA[4], accB[4];
    #pragma unroll
    for (int t = 0; t < 4; t++) { accA[t] = (f32x2){0.f, 0.f}; accB[t] = (f32x2){0.f, 0.f}; }
    int2 seA = rowse[wid0];
    int2 seB = rowse[wid1];
    int ia = seA.x + lane, ib = seB.x + lane;
    int jA = (ia < seA.y) ? col_idx[ia] : N;     // tail / overhang lanes -> shared zero row
    int jB = (ib < seB.y) ? col_idx[ib] : N;
    // cnt values are wave-uniform (wid0/wid1 uniform per wave) -> scalarize for scalar branches
    int cntA = __builtin_amdgcn_readfirstlane(min(64, seA.y - seA.x));
    int cntB = __builtin_amdgcn_readfirstlane(min(64, seB.y - seB.x));
    int mx = max(cntA, cntB);
    for (int i = 0; i < mx; i += 8) {
        uint4 ra0, ra1, rb0, rb1;
        const bool dA = i < cntA, dB = i < cntB;   // wave-uniform
        if (dA) {
            int a0 = __shfl(jA, i + q);
            int a1 = __shfl(jA, i + 4 + q);
            ra0 = *(const uint4*)(xwb + (size_t)a0 * D + d8);
            ra1 = *(const uint4*)(xwb + (size_t)a1 * D + d8);
        }
        if (dB) {
            int b0 = __shfl(jB, i + q);
            int b1 = __shfl(jB, i + 4 + q);
            rb0 = *(const uint4*)(xwb + (size_t)b0 * D + d8);
            rb1 = *(const uint4*)(xwb + (size_t)b1 * D + d8);
        }
        if (dA) { add_row(accA, ra0); add_row(accA, ra1); }
        if (dB) { add_row(accB, rb0); add_row(accB, rb1); }
    }
    // cold long-degree remainder (deg+1 > 64), fully inlined
    for (int e = seA.x + 64; e < seA.y; e += 64) {
        int idx = e + lane;
        int j = (idx < seA.y) ? col_idx[idx] : N;
        int cnt = min(64, seA.y - e);
        for (int i = 0; i < cnt; i += 8) {
            int j0 = __shfl(j, i + q);
            int j1 = __shfl(j, i + 4 + q);
            add_row(accA, *(const uint4*)(xwb + (size_t)j0 * D + d8));
            add_row(accA, *(const uint4*)(xwb + (size_t)j1 * D + d8));
        }
    }
    for (int e = seB.x + 64; e < seB.y; e += 64) {
        int idx = e + lane;
        int j = (idx < seB.y) ? col_idx[idx] : N;
        int cnt = min(64, seB.y - e);
        for (int i = 0; i < cnt; i += 8) {
            int j0 = __shfl(j, i + q);
            int j1 = __shfl(j, i + 4 + q);
            add_row(accB, *(const uint4*)(xwb + (size_t)j0 * D + d8));
            add_row(accB, *(const uint4*)(xwb + (size_t)j1 * D + d8));
        }
    }

    float av0[8] = {accA[0].x, accA[0].y, accA[1].x, accA[1].y, accA[2].x, accA[2].y, accA[3].x, accA[3].y};
    float av1[8] = {accB[0].x, accB[0].y, accB[1].x, accB[1].y, accB[2].x, accB[2].y, accB[3].x, accB[3].y};
    #pragma unroll
    for (int t = 0; t < 8; t++) {
        av0[t] += __shfl_xor(av0[t], 16);
        av0[t] += __shfl_xor(av0[t], 32);
        av1[t] += __shfl_xor(av1[t], 16);
        av1[t] += __shfl_xor(av1[t], 32);
    }
    float4 ba = *(const float4*)(bias + d8);
    float4 bb = *(const float4*)(bias + d8 + 4);
    r0[0] = fmaxf(av0[0] + ba.x, 0.f);
    r0[1] = fmaxf(av0[1] + ba.y, 0.f);
    r0[2] = fmaxf(av0[2] + ba.z, 0.f);
    r0[3] = fmaxf(av0[3] + ba.w, 0.f);
    r0[4] = fmaxf(av0[4] + bb.x, 0.f);
    r0[5] = fmaxf(av0[5] + bb.y, 0.f);
    r0[6] = fmaxf(av0[6] + bb.z, 0.f);
    r0[7] = fmaxf(av0[7] + bb.w, 0.f);
    r1[0] = fmaxf(av1[0] + ba.x, 0.f);
    r1[1] = fmaxf(av1[1] + ba.y, 0.f);
    r1[2] = fmaxf(av1[2] + ba.z, 0.f);
    r1[3] = fmaxf(av1[3] + ba.w, 0.f);
    r1[4] = fmaxf(av1[4] + bb.x, 0.f);
    r1[5] = fmaxf(av1[5] + bb.y, 0.f);
    r1[6] = fmaxf(av1[6] + bb.z, 0.f);
    r1[7] = fmaxf(av1[7] + bb.w, 0.f);
}

// ---------------- dispatch 3: fused layer-1 aggregate + layer-1 GEMM ----------------
// block = 16 nodes, 4 waves. Wave w gathers nodes w*4..w*4+3 (two interleaved pairs) -> bf16 h rows
// in LDS (pad 136); then wave w computes output cols 32w..32w+31 via 8 MFMAs; LDS transpose; store.
__global__ __launch_bounds__(256) void agg_gemm1(const u16* __restrict__ xwb, const int2* __restrict__ rowse,
                                                 const int* __restrict__ col_idx, const float* __restrict__ bias,
                                                 const u16* __restrict__ Wp, u16* __restrict__ outb, int N) {
    __shared__ u16 hs[16 * 136];
    __shared__ u16 Cs[16 * 136];
    const int tid = threadIdx.x;
    const int wave = tid >> 6, lane = tid & 63, quad = lane >> 4, l16 = lane & 15;
    const int tile = blockIdx.x * 16;
    const int d8 = l16 * 8;
    #pragma unroll
    for (int m = 0; m < 4; m += 2) {
        int nl0 = wave * 4 + m, nl1 = nl0 + 1;
        int wid0 = tile + nl0, wid1 = tile + nl1;
        float r0[8], r1[8];
        int g0 = min(wid0, N - 1), g1 = min(wid1, N - 1);   // clamp pad nodes to a valid CSR row
        gather2(xwb, rowse, col_idx, bias, g0, g1, lane, N, quad, d8, r0, r1);
        if (quad == 0) {
            uint4 o0, o1;
            if (wid0 < N) {
                o0.x = pack_bf16x2(r0[0], r0[1]);
                o0.y = pack_bf16x2(r0[2], r0[3]);
                o0.z = pack_bf16x2(r0[4], r0[5]);
                o0.w = pack_bf16x2(r0[6], r0[7]);
            } else o0 = make_uint4(0, 0, 0, 0);
            if (wid1 < N) {
                o1.x = pack_bf16x2(r1[0], r1[1]);
                o1.y = pack_bf16x2(r1[2], r1[3]);
                o1.z = pack_bf16x2(r1[4], r1[5]);
                o1.w = pack_bf16x2(r1[6], r1[7]);
            } else o1 = make_uint4(0, 0, 0, 0);
            *(uint4*)(hs + nl0 * 136 + d8) = o0;
            *(uint4*)(hs + nl1 * 136 + d8) = o1;
        }
    }
    __syncthreads();
    // A-frags from LDS: row m = l16, k = kt*32 + quad*8 + j  (stride 136 -> <=2-way bank alias)
    short8 af[4];
    #pragma unroll
    for (int kt = 0; kt < 4; kt++)
        af[kt] = *(const short8*)(hs + l16 * 136 + kt * 32 + quad * 8);
    f32x4 acc[2];
    acc[0] = (f32x4){0.f, 0.f, 0.f, 0.f};
    acc[1] = (f32x4){0.f, 0.f, 0.f, 0.f};
    #pragma unroll
    for (int kt = 0; kt < 4; kt++) {
        #pragma unroll
        for (int t = 0; t < 2; t++) {
            int nt = wave * 2 + t;
            short8 bf = *(const short8*)(Wp + ((size_t)(nt * 4 + kt) * 64 + lane) * 8);
            acc[t] = __builtin_amdgcn_mfma_f32_16x16x32_bf16(af[kt], bf, acc[t], 0, 0, 0);
        }
    }
    // C layout col=lane&15 (within nt tile), row=quad*4+reg -> Cs transpose
    #pragma unroll
    for (int t = 0; t < 2; t++) {
        int nt = wave * 2 + t;
        #pragma unroll
        for (int r = 0; r < 4; r++)
            Cs[(quad * 4 + r) * 136 + nt * 16 + l16] = f32_to_bf16(acc[t][r]);
    }
    __syncthreads();
    // coalesced store: 16 rows x 16 uint4 chunks = 256 threads, one each
    {
        int row = tid >> 4, chunk = tid & 15;
        int grow = tile + row;
        if (grow <= N)      // row N = zero pad row for agg_head tails
            *(uint4*)(outb + (size_t)grow * 128 + chunk * 8) =
                *(const uint4*)(Cs + row * 136 + chunk * 8);
    }
}

// ---------------- dispatch 4: layer-2 aggregate fused with head -> out12 (two nodes per wave) ----------------
// (round-4/6 lessons: per-node global atomics serialize on contended graph lines (72->155us);
//  LDS-staged flush couples waves via __syncthreads (72->102us). Independent waves + separate
//  4us graph_mean kernel is the winner — launch overhead measured ~0 in round 6.)
__global__ __launch_bounds__(256) void agg_head(const u16* __restrict__ xwb, const int2* __restrict__ rowse,
                                                const int* __restrict__ col_idx, const float* __restrict__ bias,
                                                const float* __restrict__ Wfp, const float* __restrict__ bfv,
                                                float* __restrict__ out12, int N) {
    int wpair = (blockIdx.x * 256 + threadIdx.x) >> 6;
    int wid0 = wpair * 2;
    if (wid0 >= N) return;
    int wid1 = min(wid0 + 1, N - 1);
    int lane = threadIdx.x & 63;
    const int q = lane >> 4;
    const int d8 = (lane & 15) * 8;
    // issue head-weight loads early (independent of gather) — 6 coalesced float4, shared by both nodes
    float w[24];
    const float* wp = Wfp + lane * 24;
    #pragma unroll
    for (int i = 0; i < 6; i++) *(float4*)(w + i * 4) = *(const float4*)(wp + i * 4);
    float r0[8], r1[8];
    gather2(xwb, rowse, col_idx, bias, wid0, wid1, lane, N, q, d8, r0, r1);
    const int t0 = 3 * q;
    float p00 = 0.f, p01 = 0.f, p02 = 0.f;
    float p10 = 0.f, p11 = 0.f, p12 = 0.f;
    #pragma unroll
    for (int k = 0; k < 8; k++) {
        p00 += r0[k] * w[k * 3];
        p01 += r0[k] * w[k * 3 + 1];
        p02 += r0[k] * w[k * 3 + 2];
        p10 += r1[k] * w[k * 3];
        p11 += r1[k] * w[k * 3 + 1];
        p12 += r1[k] * w[k * 3 + 2];
    }
    #pragma unroll
    for (int m = 1; m <= 8; m <<= 1) {
        p00 += __shfl_xor(p00, m);
        p01 += __shfl_xor(p01, m);
        p02 += __shfl_xor(p02, m);
        p10 += __shfl_xor(p10, m);
        p11 += __shfl_xor(p11, m);
        p12 += __shfl_xor(p12, m);
    }
    if ((lane & 15) == 0) {
        float b0 = bfv[t0], b1 = bfv[t0 + 1], b2 = bfv[t0 + 2];
        float* o0 = out12 + (size_t)wid0 * 12 + t0;
        o0[0] = 1.f / (1.f + __expf(-(p00 + b0)));
        o0[1] = 1.f / (1.f + __expf(-(p01 + b1)));
        o0[2] = 1.f / (1.f + __expf(-(p02 + b2)));
        if (wid0 + 1 < N) {
            float* o1 = out12 + (size_t)wid1 * 12 + t0;
            o1[0] = 1.f / (1.f + __expf(-(p10 + b0)));
            o1[1] = 1.f / (1.f + __expf(-(p11 + b1)));
            o1[2] = 1.f / (1.f + __expf(-(p12 + b2)));
        }
    }
}

// ---------------- dispatch 5: per-graph mean over out12 ----------------
__global__ __launch_bounds__(128) void graph_mean(const float* __restrict__ out12, const int* __restrict__ goff,
                                                  float* __restrict__ out, int G) {
    __shared__ float partial[120];
    int g = blockIdx.x;
    int tid = threadIdx.x;
    int start = goff[g];
    int size = goff[g + 1] - start;
    if (tid < 120) {
        int t = tid % 12, chunk = tid / 12;
        float s = 0.f;
        for (int i = chunk; i < size; i += 10)
            s += out12[(size_t)(start + i) * 12 + t];
        partial[tid] = s;
    }
    __syncthreads();
    if (tid < 12) {
        float tot = 0.f;
        #pragma unroll
        for (int c = 0; c < 10; c++) tot += partial[c * 12 + tid];
        out[(size_t)g * 12 + tid] = tot / (float)size;
    }
}

// ---------------- launch ----------------

extern "C" void kernel_launch(void* const* d_in, const int* in_sizes, int n_in,
                              void* d_out, int out_size, void* d_ws, size_t ws_size,
                              hipStream_t stream) {
    const float* X   = (const float*)d_in[0];
    const int* edges = (const int*)d_in[1];
    const int* gsz   = (const int*)d_in[2];
    const float* W0  = (const float*)d_in[3];
    const float* b0  = (const float*)d_in[4];
    const float* W1  = (const float*)d_in[5];
    const float* b1  = (const float*)d_in[6];
    const float* Wf  = (const float*)d_in[7];
    const float* bfv = (const float*)d_in[8];
    float* out = (float*)d_out;

    const int N = in_sizes[0] / D;       // 100000
    const int E = in_sizes[1] / 2;       // 1600000
    const int G = in_sizes[2];           // 1000
    const int* esrc = edges;
    const int* edst = edges + E;
    const int nbuck = (N + 127) >> 7;    // 782
    const int nchunk = (E + PER - 1) / PER;   // 261

    // workspace layout (xwb/hb get N+64 rows: row N is the zero pad row)
    char* ws = (char*)d_ws;
    char* p = ws;
    u16* xwb     = (u16*)p;  p += (((size_t)(N + 64) * D * 2) + 255) & ~255ull;
    u16* hb      = (u16*)p;  p += (((size_t)(N + 64) * D * 2) + 255) & ~255ull;
    u16* Wp0     = (u16*)p;  p += ((size_t)128 * 128 * 2 + 255) & ~255ull;
    u16* Wp1     = (u16*)p;  p += ((size_t)128 * 128 * 2 + 255) & ~255ull;
    float* Wfp   = (float*)p; p += ((size_t)64 * 24 * 4 + 255) & ~255ull;
    u32* edgeBuf = (u32*)p;  p += (((size_t)nchunk * PER * 4) + 255) & ~255ull;              // 6.4 MB
    u16* offTab  = (u16*)p;  p += (((size_t)(NBUCK_MAX + 1) * NCHUNK_PAD * 2) + 255) & ~255ull;  // 1.05 MB
    int* col_idx = (int*)p;  p += (((size_t)nbuck * CAPB * 4) + 255) & ~255ull;              // 12.8 MB
    int2* rowse  = (int2*)p; p += (((size_t)N * 8) + 255) & ~255ull;
    float* out12 = (float*)p; p += (((size_t)N * 12 * 4) + 255) & ~255ull;                   // 4.8 MB
    int* goff    = (int*)p;

    // 1: LDS bucket-sort binning (coalesced edgeBuf runs, transposed offTab) + goff scan + Wf/W pack
    prep_place<<<nchunk + 2 + 64, 512, 0, stream>>>(esrc, edst, E, nbuck, nchunk, edgeBuf, offTab,
                                                    W0, W1, Wp0, Wp1, Wf, Wfp, gsz, G, goff);
    // 2: CSR finalize (LDS sort + coalesced col_idx flush) + layer-0 GEMM
    const int gemmGrid = (N + 63) / 64;
    finalize_gemm0<<<nbuck + gemmGrid, 256, 0, stream>>>(edgeBuf, offTab, rowse, col_idx, nbuck, nchunk,
                                                         X, Wp0, xwb, N);
    // 3: fused layer-1 aggregate + layer-1 GEMM (writes xw2 into hb, incl. zero row N)
    agg_gemm1<<<N / 16 + 1, 256, 0, stream>>>(xwb, rowse, col_idx, b0, Wp1, hb, N);
    // 4: layer-2 aggregate fused with head -> out12 (two nodes per wave, independent waves)
    const int waves2 = (N + 1) / 2;
    agg_head<<<(waves2 + 3) / 4, 256, 0, stream>>>(hb, rowse, col_idx, b1, Wfp, bfv, out12, N);
    // 5: per-graph mean
    graph_mean<<<G, 128, 0, stream>>>(out12, goff, out, G);
}